// Round 21
// baseline (750.517 us; speedup 1.0000x reference)
//
#include <hip/hip_runtime.h>

#define NB 8
#define NPTS 2048
#define KNN 20
#define OUTC 256
#define NPB 8
#define NRED 64   // second-level reduction width (blocks in k_reduce)

__global__ void k_copy_in(const float* __restrict__ in, float* __restrict__ out) {
    int t = blockIdx.x * 256 + threadIdx.x;
    int n = t & (NPTS - 1);
    int c = (t >> 11) & 63;
    int b = t >> 17;
    out[((size_t)b * OUTC + 192 + c) * NPTS + n] = in[t];
}

__global__ void k_prep_uv(const float* __restrict__ W, int Cin,
                          float* __restrict__ Ut, float* __restrict__ Vt) {
    int t = blockIdx.x * 256 + threadIdx.x;
    if (t >= Cin * 64) return;
    int o = t & 63;
    int c = t >> 6;
    float wa = W[o * (2 * Cin) + c];
    float wb = W[o * (2 * Cin) + Cin + c];
    Ut[c * 64 + o] = wa - wb;
    Vt[c * 64 + o] = wb;
}

__global__ void k_sqsum(const float* __restrict__ out, int Cin, float* __restrict__ sq) {
    int t = blockIdx.x * 256 + threadIdx.x;
    int b = t >> 11;
    int m = t & (NPTS - 1);
    const float* X = out + ((size_t)b * OUTC + (OUTC - Cin)) * NPTS;
    float s = 0.f;
    for (int c = 0; c < Cin; ++c) {
        float x = X[(size_t)c * NPTS + m];
        s = fmaf(x, x, s);
    }
    sq[t] = s;
}

// Bm stored with 8-float groups at stride 12 floats (48B): read addrs for
// tx=0..15 start at banks (12*tx)%32 -> 2-way span overlap only (~free).
#define BSW(j) (((j) >> 3) * 12 + ((j) & 7))

// Double-buffered LDS: prefetch tile k+1 into regs during compute of tile k,
// one barrier per K-iteration. FMA order identical -> dist bit-identical.
__global__ __launch_bounds__(256) void k_dist(const float* __restrict__ out, int Cin,
        const float* __restrict__ sq, float* __restrict__ dist,
        int bOff, int n0, int NR, int sym) {
    int mt, nt;
    if (sym) {                       // triangular launch: gridDim.x == 136
        int u = blockIdx.x;
        mt = 0;
        int rem = 16;
        while (u >= rem) { u -= rem; --rem; ++mt; }
        nt = mt + u;
    } else {
        mt = blockIdx.x; nt = blockIdx.y;
    }
    int bz = blockIdx.z;
    int b = bOff + bz;
    const float* X = out + ((size_t)b * OUTC + (OUTC - Cin)) * NPTS;
    int m0 = mt * 128;
    int nbase = n0 + nt * 128;
    __shared__ float An[2][16][128];
    __shared__ float Bm[2][16][192];
    int t = threadIdx.x;
    int tx = t & 15, ty = t >> 4;
    float acc[8][8];
    #pragma unroll
    for (int i = 0; i < 8; ++i)
        #pragma unroll
        for (int j = 0; j < 8; ++j) acc[i][j] = 0.f;

    int lcol = (t & 31) * 4;
    int swl = BSW(lcol);
    int lrow = t >> 5;

    // preload tile 0 into buffer 0
    #pragma unroll
    for (int i = 0; i < 2; ++i) {
        int rr = lrow + i * 8;
        const float* src = X + (size_t)rr * NPTS;
        *(float4*)&An[0][rr][lcol] = *(const float4*)&src[nbase + lcol];
        *(float4*)&Bm[0][rr][swl]  = *(const float4*)&src[m0 + lcol];
    }
    __syncthreads();

    int cur = 0;
    for (int kk = 0; kk < Cin; kk += 16) {
        float4 pa0, pa1, pb0, pb1;
        bool more = (kk + 16 < Cin);
        if (more) {                   // issue prefetch loads early
            const float* s0 = X + (size_t)(kk + 16 + lrow) * NPTS;
            const float* s1 = X + (size_t)(kk + 16 + lrow + 8) * NPTS;
            pa0 = *(const float4*)&s0[nbase + lcol];
            pb0 = *(const float4*)&s0[m0 + lcol];
            pa1 = *(const float4*)&s1[nbase + lcol];
            pb1 = *(const float4*)&s1[m0 + lcol];
        }
        #pragma unroll
        for (int k = 0; k < 16; ++k) {
            float av[8], bv[8];
            *(float4*)&av[0] = *(float4*)&An[cur][k][ty * 8];
            *(float4*)&av[4] = *(float4*)&An[cur][k][ty * 8 + 4];
            *(float4*)&bv[0] = *(float4*)&Bm[cur][k][tx * 12];
            *(float4*)&bv[4] = *(float4*)&Bm[cur][k][tx * 12 + 4];
            #pragma unroll
            for (int ia = 0; ia < 8; ++ia)
                #pragma unroll
                for (int ib = 0; ib < 8; ++ib)
                    acc[ia][ib] = fmaf(av[ia], bv[ib], acc[ia][ib]);
        }
        if (more) {                   // write into inactive buffer (no race)
            int nb = cur ^ 1;
            *(float4*)&An[nb][lrow][lcol]     = pa0;
            *(float4*)&Bm[nb][lrow][swl]      = pb0;
            *(float4*)&An[nb][lrow + 8][lcol] = pa1;
            *(float4*)&Bm[nb][lrow + 8][swl]  = pb1;
        }
        __syncthreads();
        cur ^= 1;
    }

    const float* sqb = sq + b * NPTS;
    float sqm[8];
    *(float4*)&sqm[0] = *(const float4*)&sqb[m0 + tx * 8];
    *(float4*)&sqm[4] = *(const float4*)&sqb[m0 + tx * 8 + 4];
    float* dbase = dist + (size_t)bz * NR * NPTS;
    #pragma unroll
    for (int ia = 0; ia < 8; ++ia) {
        int rn = nt * 128 + ty * 8 + ia;
        float ov[8];
        #pragma unroll
        for (int ib = 0; ib < 8; ++ib) ov[ib] = 2.f * acc[ia][ib] - sqm[ib];
        *(float4*)&dbase[(size_t)rn * NPTS + m0 + tx * 8]     = *(float4*)&ov[0];
        *(float4*)&dbase[(size_t)rn * NPTS + m0 + tx * 8 + 4] = *(float4*)&ov[4];
    }
    if (sym && mt < nt) {
        float sqn[8];
        *(float4*)&sqn[0] = *(const float4*)&sqb[nbase + ty * 8];
        *(float4*)&sqn[4] = *(const float4*)&sqb[nbase + ty * 8 + 4];
        #pragma unroll
        for (int ib = 0; ib < 8; ++ib) {
            int rm = m0 + tx * 8 + ib;
            float ov[8];
            #pragma unroll
            for (int ia = 0; ia < 8; ++ia) ov[ia] = 2.f * acc[ia][ib] - sqn[ia];
            *(float4*)&dbase[(size_t)rm * NPTS + nbase + ty * 8]     = *(float4*)&ov[0];
            *(float4*)&dbase[(size_t)rm * NPTS + nbase + ty * 8 + 4] = *(float4*)&ov[4];
        }
    }
}

// col of candidate j (float4-load layout): 4*lane + (j&3) + 256*(j>>2)
#define SCOLX(lane, j) (((lane) << 2) + ((j) & 3) + (((j) >> 2) << 8))

// monotone f32 -> u32 key (no NaNs), then (key<<32)|~col: u64 desc order
// == (value desc, col asc) exactly; keys unique since cols unique.
// Empty slot = 0 (below any real key).
__device__ __forceinline__ unsigned long long packkey(float v, int c) {
    unsigned u = __float_as_uint(v);
    u ^= ((unsigned)((int)u >> 31)) | 0x80000000u;
    return ((unsigned long long)u << 32) | (unsigned)(~c);
}

// Tree-ILP threshold scan, fully in u64 key space.
__device__ __forceinline__ void scan4k(const float (&v)[32], int lane,
        unsigned long long thrK,
        unsigned long long& a1, unsigned long long& a2,
        unsigned long long& a3, unsigned long long& a4, int& d) {
    unsigned long long tK = thrK;
    d = 0;
    #pragma unroll
    for (int p = 0; p < 4; ++p) {
        unsigned long long b0 = 0, b1 = 0, b2 = 0, b3 = 0;
        #pragma unroll
        for (int jj = 0; jj < 8; ++jj) {
            {
                int j = jj;
                unsigned long long kj = packkey(v[j], SCOLX(lane, j));
                if (kj < tK && kj > b0) b0 = kj;
            }
            {
                int j = 8 + jj;
                unsigned long long kj = packkey(v[j], SCOLX(lane, j));
                if (kj < tK && kj > b1) b1 = kj;
            }
            {
                int j = 16 + jj;
                unsigned long long kj = packkey(v[j], SCOLX(lane, j));
                if (kj < tK && kj > b2) b2 = kj;
            }
            {
                int j = 24 + jj;
                unsigned long long kj = packkey(v[j], SCOLX(lane, j));
                if (kj < tK && kj > b3) b3 = kj;
            }
        }
        if (b1 > b0) b0 = b1;
        if (b3 > b2) b2 = b3;
        if (b2 > b0) b0 = b2;
        if (p == 0)      a1 = b0;
        else if (p == 1) a2 = b0;
        else if (p == 2) a3 = b0;
        else             a4 = b0;
        if (b0 != 0) ++d;
        tK = b0;
    }
}

// Top-20 per row: per-lane sorted top-4 head window (u64 keys) + one
// u64 max-butterfly per selection. Exact (value desc, col asc).
__global__ __launch_bounds__(256) void k_select(const float* __restrict__ dist,
        int* __restrict__ idx, int bOff, int n0, int NR) {
    int lane = threadIdx.x & 63;
    int r = blockIdx.x * 4 + (threadIdx.x >> 6);
    int bl = r / NR;
    int n = n0 + (r - bl * NR);
    const float4* row4 = (const float4*)(dist + (size_t)r * NPTS);
    float v[32];
    #pragma unroll
    for (int jj = 0; jj < 8; ++jj)
        *(float4*)&v[jj * 4] = row4[lane + 64 * jj];
    int* orow = idx + ((size_t)(bOff + bl) * NPTS + n) * KNN;

    unsigned long long a1, a2, a3, a4;
    int d;
    unsigned long long mlK = 0xFFFFFFFFFFFFFFFFull;
    scan4k(v, lane, mlK, a1, a2, a3, a4, d);

    for (int s = 0; s < KNN; ++s) {
        unsigned long long wk = a1;
        #pragma unroll
        for (int off = 32; off; off >>= 1) {
            unsigned long long ok = __shfl_xor(wk, off);
            if (ok > wk) wk = ok;
        }
        int wc = ~(int)(unsigned)(wk & 0xFFFFFFFFull);
        if (lane == 0) orow[s] = wc;
        bool won = (a1 != 0) && (wk == a1);
        if (won) {
            mlK = a1;
            a1 = a2; a2 = a3; a3 = a4; a4 = 0;
            --d;
        }
        if (s < KNN - 1 && __any(won && d == 0)) {
            if (won && d == 0)
                scan4k(v, lane, mlK, a1, a2, a3, a4, d);
        }
    }
}

__global__ __launch_bounds__(256) void k_pz(const float* __restrict__ out, int Cin,
        const float* __restrict__ Ut, const float* __restrict__ Vt,
        float* __restrict__ P, float* __restrict__ Z) {
    int b = blockIdx.y;
    int n0 = blockIdx.x * 64;
    const float* X = out + ((size_t)b * OUTC + (OUTC - Cin)) * NPTS;
    __shared__ float Xs[16][64];
    __shared__ float Us[16][64];
    __shared__ float Vs[16][64];
    int t = threadIdx.x;
    int tx = t & 15, ty = t >> 4;
    float accP[4][4] = {}, accZ[4][4] = {};
    int col = t & 63, r0 = t >> 6;
    for (int kk = 0; kk < Cin; kk += 16) {
        #pragma unroll
        for (int i = 0; i < 4; ++i) {
            int rr = r0 + i * 4;
            Xs[rr][col] = X[(size_t)(kk + rr) * NPTS + n0 + col];
            Us[rr][col] = Ut[(kk + rr) * 64 + col];
            Vs[rr][col] = Vt[(kk + rr) * 64 + col];
        }
        __syncthreads();
        #pragma unroll
        for (int k = 0; k < 16; ++k) {
            float xv[4], uv[4], vv[4];
            *(float4*)xv = *(float4*)&Xs[k][ty * 4];
            *(float4*)uv = *(float4*)&Us[k][tx * 4];
            *(float4*)vv = *(float4*)&Vs[k][tx * 4];
            #pragma unroll
            for (int a = 0; a < 4; ++a)
                #pragma unroll
                for (int o = 0; o < 4; ++o) {
                    accP[a][o] = fmaf(uv[o], xv[a], accP[a][o]);
                    accZ[a][o] = fmaf(vv[o], xv[a], accZ[a][o]);
                }
        }
        __syncthreads();
    }
    #pragma unroll
    for (int a = 0; a < 4; ++a) {
        size_t base = ((size_t)b * NPTS + n0 + ty * 4 + a) * 64 + tx * 4;
        *(float4*)&P[base] = *(float4*)&accP[a][0];
        *(float4*)&Z[base] = *(float4*)&accZ[a][0];
    }
}

__global__ __launch_bounds__(64) void k_gather(const int* __restrict__ idx,
        const float* __restrict__ P, const float* __restrict__ Z,
        const float* __restrict__ bias,
        float* __restrict__ ymax, float* __restrict__ ymin,
        float* __restrict__ partials) {
    int blk = blockIdx.x;
    int b = blk / (NPTS / NPB);
    int n0 = (blk % (NPTS / NPB)) * NPB;
    int o = threadIdx.x;
    float bv = bias[o];
    float S1 = 0.f, S2 = 0.f;
    const float* Zb = Z + (size_t)b * NPTS * 64;
    for (int i = 0; i < NPB; ++i) {
        int n = n0 + i;
        const int* ir = idx + ((size_t)b * NPTS + n) * KNN;
        float mx = -3.0e38f, mn = 3.0e38f, s1 = 0.f, s2 = 0.f;
        #pragma unroll
        for (int k = 0; k < KNN; ++k) {
            int m = ir[k];
            float zv = Zb[(size_t)m * 64 + o];
            mx = fmaxf(mx, zv);
            mn = fminf(mn, zv);
            s1 += zv;
            s2 = fmaf(zv, zv, s2);
        }
        float tv = P[((size_t)b * NPTS + n) * 64 + o] + bv;
        size_t yb = ((size_t)b * NPTS + n) * 64 + o;
        ymax[yb] = tv + mx;
        ymin[yb] = tv + mn;
        S1 += (float)KNN * tv + s1;
        S2 += fmaf((float)KNN * tv, tv, fmaf(2.f * tv, s1, s2));
    }
    partials[(size_t)blk * 128 + o] = S1;
    partials[(size_t)blk * 128 + 64 + o] = S2;
}

// Level-1 reduce: partials[2048][128] -> red[NRED][128]. Coalesced row reads.
__global__ __launch_bounds__(256) void k_reduce(const float* __restrict__ partials,
                                                float* __restrict__ red) {
    __shared__ float L[256];
    int t = threadIdx.x;
    int j = t & 127, half = t >> 7;
    int rows = (NB * NPTS / NPB) / NRED;              // 32 rows per block
    int base = blockIdx.x * rows + half;
    float s = 0.f;
    #pragma unroll
    for (int i = 0; i < 16; ++i)
        s += partials[(size_t)(base + 2 * i) * 128 + j];
    L[t] = s;
    __syncthreads();
    if (half == 0)
        red[(size_t)blockIdx.x * 128 + j] = L[j] + L[128 + j];
}

__global__ void k_stats(const float* __restrict__ red,
        const float* __restrict__ gamma, const float* __restrict__ beta,
        float* __restrict__ ss) {
    __shared__ float L[128];
    int j = threadIdx.x;
    float s = 0.f;
    #pragma unroll
    for (int p = 0; p < NRED; ++p) s += red[(size_t)p * 128 + j];
    L[j] = s;
    __syncthreads();
    if (j < 64) {
        const float cnt = (float)NB * NPTS * KNN;
        float mu = L[j] / cnt;
        float ms = L[64 + j] / cnt;
        float var = ms - mu * mu;
        float sc = gamma[j] / sqrtf(var + 1e-5f);
        ss[j] = sc;
        ss[64 + j] = beta[j] - mu * sc;
    }
}

__global__ __launch_bounds__(256) void k_final(const float* __restrict__ ymax,
        const float* __restrict__ ymin, const float* __restrict__ ss,
        float* __restrict__ out, int obase) {
    int b = blockIdx.y;
    int n0 = blockIdx.x * 64;
    __shared__ float T[64][65];
    int t = threadIdx.x;
    int o = t & 63, r0 = t >> 6;
    float sc = ss[o], sh = ss[64 + o];
    #pragma unroll
    for (int i = 0; i < 16; ++i) {
        int n = r0 + i * 4;
        size_t src = ((size_t)b * NPTS + n0 + n) * 64 + o;
        float v = (sc >= 0.f) ? ymax[src] : ymin[src];
        v = fmaf(sc, v, sh);
        T[o][n] = v > 0.f ? v : 0.f;
    }
    __syncthreads();
    #pragma unroll
    for (int i = 0; i < 16; ++i) {
        int oo = r0 + i * 4;
        out[((size_t)b * OUTC + obase + oo) * NPTS + n0 + o] = T[oo][o];
    }
}

extern "C" void kernel_launch(void* const* d_in, const int* in_sizes, int n_in,
                              void* d_out, int out_size, void* d_ws, size_t ws_size,
                              hipStream_t stream) {
    const float* inp   = (const float*)d_in[0];
    const float* W[3]  = {(const float*)d_in[1], (const float*)d_in[5], (const float*)d_in[9]};
    const float* bi[3] = {(const float*)d_in[2], (const float*)d_in[6], (const float*)d_in[10]};
    const float* ga[3] = {(const float*)d_in[3], (const float*)d_in[7], (const float*)d_in[11]};
    const float* be[3] = {(const float*)d_in[4], (const float*)d_in[8], (const float*)d_in[12]};
    float* out = (float*)d_out;
    (void)in_sizes; (void)n_in; (void)out_size;

    char* w = (char*)d_ws;
    size_t off = 0;
    auto alloc = [&](size_t bytes) -> void* {
        void* p = w + off;
        off = (off + bytes + 255) & ~(size_t)255;
        return p;
    };
    int*   idx      = (int*)  alloc((size_t)NB * NPTS * KNN * 4);
    float* Ut       = (float*)alloc(192 * 64 * 4);
    float* Vt       = (float*)alloc(192 * 64 * 4);
    float* sq       = (float*)alloc((size_t)NB * NPTS * 4);
    float* P        = (float*)alloc((size_t)NB * NPTS * 64 * 4);
    float* Z        = (float*)alloc((size_t)NB * NPTS * 64 * 4);
    float* ymax     = (float*)alloc((size_t)NB * NPTS * 64 * 4);
    float* ymin     = (float*)alloc((size_t)NB * NPTS * 64 * 4);
    float* partials = (float*)alloc((size_t)(NB * NPTS / NPB) * 128 * 4);
    float* red      = (float*)alloc((size_t)NRED * 128 * 4);
    float* ss       = (float*)alloc(128 * 4);

    float* dist = (float*)(w + off);
    size_t distAvail = (ws_size > off) ? (ws_size - off) : 0;
    const size_t matBytes = (size_t)NPTS * NPTS * 4;

    k_copy_in<<<NB * 64 * NPTS / 256, 256, 0, stream>>>(inp, out);

    int Cins[3]  = {64, 128, 192};
    int obase[3] = {128, 64, 0};
    int nblkGather = NB * NPTS / NPB;

    for (int l = 0; l < 3; ++l) {
        int Cin = Cins[l];
        k_prep_uv<<<(Cin * 64 + 255) / 256, 256, 0, stream>>>(W[l], Cin, Ut, Vt);
        k_sqsum<<<NB * NPTS / 256, 256, 0, stream>>>(out, Cin, sq);

        if (distAvail >= (size_t)NB * matBytes) {
            k_dist<<<dim3(136, 1, NB), 256, 0, stream>>>(out, Cin, sq, dist, 0, 0, NPTS, 1);
            k_select<<<NB * NPTS / 4, 256, 0, stream>>>(dist, idx, 0, 0, NPTS);
        } else if (distAvail >= matBytes) {
            for (int b = 0; b < NB; ++b) {
                k_dist<<<dim3(136, 1, 1), 256, 0, stream>>>(out, Cin, sq, dist, b, 0, NPTS, 1);
                k_select<<<NPTS / 4, 256, 0, stream>>>(dist, idx, b, 0, NPTS);
            }
        } else {
            int NR = (int)((distAvail / ((size_t)NPTS * 4)) & ~(size_t)127);
            if (NR < 128) NR = 128;
            for (int b = 0; b < NB; ++b) {
                for (int n0 = 0; n0 < NPTS; n0 += NR) {
                    int nr = (NPTS - n0 < NR) ? (NPTS - n0) : NR;
                    k_dist<<<dim3(16, nr / 128, 1), 256, 0, stream>>>(out, Cin, sq, dist, b, n0, nr, 0);
                    k_select<<<nr / 4, 256, 0, stream>>>(dist, idx, b, n0, nr);
                }
            }
        }

        k_pz<<<dim3(NPTS / 64, NB), 256, 0, stream>>>(out, Cin, Ut, Vt, P, Z);
        k_gather<<<nblkGather, 64, 0, stream>>>(idx, P, Z, bi[l], ymax, ymin, partials);
        k_reduce<<<NRED, 256, 0, stream>>>(partials, red);
        k_stats<<<1, 128, 0, stream>>>(red, ga[l], be[l], ss);
        k_final<<<dim3(NPTS / 64, NB), 256, 0, stream>>>(ymax, ymin, ss, out, obase[l]);
    }
}

// Round 24
// 598.075 us; speedup vs baseline: 1.2549x; 1.2549x over previous
//
#include <hip/hip_runtime.h>

#define NB 8
#define NPTS 2048
#define KNN 20
#define OUTC 256
#define NPB 8
#define NRED 64   // second-level reduction width (blocks in k_reduce)

__global__ void k_copy_in(const float* __restrict__ in, float* __restrict__ out) {
    int t = blockIdx.x * 256 + threadIdx.x;
    int n = t & (NPTS - 1);
    int c = (t >> 11) & 63;
    int b = t >> 17;
    out[((size_t)b * OUTC + 192 + c) * NPTS + n] = in[t];
}

__global__ void k_prep_uv(const float* __restrict__ W, int Cin,
                          float* __restrict__ Ut, float* __restrict__ Vt) {
    int t = blockIdx.x * 256 + threadIdx.x;
    if (t >= Cin * 64) return;
    int o = t & 63;
    int c = t >> 6;
    float wa = W[o * (2 * Cin) + c];
    float wb = W[o * (2 * Cin) + Cin + c];
    Ut[c * 64 + o] = wa - wb;
    Vt[c * 64 + o] = wb;
}

__global__ void k_sqsum(const float* __restrict__ out, int Cin, float* __restrict__ sq) {
    int t = blockIdx.x * 256 + threadIdx.x;
    int b = t >> 11;
    int m = t & (NPTS - 1);
    const float* X = out + ((size_t)b * OUTC + (OUTC - Cin)) * NPTS;
    float s = 0.f;
    for (int c = 0; c < Cin; ++c) {
        float x = X[(size_t)c * NPTS + m];
        s = fmaf(x, x, s);
    }
    sq[t] = s;
}

// 64x64-tile sym dist: 4224 blocks (16.5/CU) for occupancy; 16 acc regs.
// Per-output fmaf order (k ascending) identical to 128-tile -> bit-identical.
__global__ __launch_bounds__(256) void k_dist64(const float* __restrict__ out, int Cin,
        const float* __restrict__ sq, float* __restrict__ dist) {
    int u = blockIdx.x;              // triangular: 528 = 32*33/2
    int mt = 0;
    int rem = 32;
    while (u >= rem) { u -= rem; --rem; ++mt; }
    int nt = mt + u;
    int b = blockIdx.z;
    const float* X = out + ((size_t)b * OUTC + (OUTC - Cin)) * NPTS;
    int m0 = mt * 64;
    int nbase = nt * 64;
    __shared__ float An[16][64];
    __shared__ float Bm[16][64];
    int t = threadIdx.x;
    int tx = t & 15, ty = t >> 4;
    float acc[4][4];
    #pragma unroll
    for (int i = 0; i < 4; ++i)
        #pragma unroll
        for (int j = 0; j < 4; ++j) acc[i][j] = 0.f;

    int lcol = (t & 15) * 4;
    int lrow = t >> 4;
    for (int kk = 0; kk < Cin; kk += 16) {
        const float* src = X + (size_t)(kk + lrow) * NPTS;
        *(float4*)&An[lrow][lcol] = *(const float4*)&src[nbase + lcol];
        *(float4*)&Bm[lrow][lcol] = *(const float4*)&src[m0 + lcol];
        __syncthreads();
        #pragma unroll
        for (int k = 0; k < 16; ++k) {
            float av[4], bv[4];
            *(float4*)&av[0] = *(float4*)&An[k][ty * 4];
            *(float4*)&bv[0] = *(float4*)&Bm[k][tx * 4];
            #pragma unroll
            for (int ia = 0; ia < 4; ++ia)
                #pragma unroll
                for (int ib = 0; ib < 4; ++ib)
                    acc[ia][ib] = fmaf(av[ia], bv[ib], acc[ia][ib]);
        }
        __syncthreads();
    }
    const float* sqb = sq + b * NPTS;
    float sqm[4];
    *(float4*)&sqm[0] = *(const float4*)&sqb[m0 + tx * 4];
    float* dbase = dist + (size_t)b * NPTS * NPTS;
    #pragma unroll
    for (int ia = 0; ia < 4; ++ia) {
        int rn = nbase + ty * 4 + ia;
        float ov[4];
        #pragma unroll
        for (int ib = 0; ib < 4; ++ib) ov[ib] = 2.f * acc[ia][ib] - sqm[ib];
        *(float4*)&dbase[(size_t)rn * NPTS + m0 + tx * 4] = *(float4*)&ov[0];
    }
    if (mt < nt) {
        float sqn[4];
        *(float4*)&sqn[0] = *(const float4*)&sqb[nbase + ty * 4];
        #pragma unroll
        for (int ib = 0; ib < 4; ++ib) {
            int rm = m0 + tx * 4 + ib;
            float ov[4];
            #pragma unroll
            for (int ia = 0; ia < 4; ++ia) ov[ia] = 2.f * acc[ia][ib] - sqn[ia];
            *(float4*)&dbase[(size_t)rm * NPTS + nbase + ty * 4] = *(float4*)&ov[0];
        }
    }
}

// Bm stored with 8-float groups at stride 12 floats (48B). Fallback-path kernel.
#define BSW(j) (((j) >> 3) * 12 + ((j) & 7))

__global__ __launch_bounds__(256) void k_dist(const float* __restrict__ out, int Cin,
        const float* __restrict__ sq, float* __restrict__ dist,
        int bOff, int n0, int NR, int sym) {
    int mt, nt;
    if (sym) {
        int u = blockIdx.x;
        mt = 0;
        int rem = 16;
        while (u >= rem) { u -= rem; --rem; ++mt; }
        nt = mt + u;
    } else {
        mt = blockIdx.x; nt = blockIdx.y;
    }
    int bz = blockIdx.z;
    int b = bOff + bz;
    const float* X = out + ((size_t)b * OUTC + (OUTC - Cin)) * NPTS;
    int m0 = mt * 128;
    int nbase = n0 + nt * 128;
    __shared__ float An[16][128];
    __shared__ float Bm[16][192];
    int t = threadIdx.x;
    int tx = t & 15, ty = t >> 4;
    float acc[8][8];
    #pragma unroll
    for (int i = 0; i < 8; ++i)
        #pragma unroll
        for (int j = 0; j < 8; ++j) acc[i][j] = 0.f;

    int lcol = (t & 31) * 4;
    int swl = BSW(lcol);
    int lrow = t >> 5;
    for (int kk = 0; kk < Cin; kk += 16) {
        #pragma unroll
        for (int i = 0; i < 2; ++i) {
            int rr = lrow + i * 8;
            const float* src = X + (size_t)(kk + rr) * NPTS;
            *(float4*)&An[rr][lcol] = *(const float4*)&src[nbase + lcol];
            *(float4*)&Bm[rr][swl]  = *(const float4*)&src[m0 + lcol];
        }
        __syncthreads();
        #pragma unroll
        for (int k = 0; k < 16; ++k) {
            float av[8], bv[8];
            *(float4*)&av[0] = *(float4*)&An[k][ty * 8];
            *(float4*)&av[4] = *(float4*)&An[k][ty * 8 + 4];
            *(float4*)&bv[0] = *(float4*)&Bm[k][tx * 12];
            *(float4*)&bv[4] = *(float4*)&Bm[k][tx * 12 + 4];
            #pragma unroll
            for (int ia = 0; ia < 8; ++ia)
                #pragma unroll
                for (int ib = 0; ib < 8; ++ib)
                    acc[ia][ib] = fmaf(av[ia], bv[ib], acc[ia][ib]);
        }
        __syncthreads();
    }
    const float* sqb = sq + b * NPTS;
    float sqm[8];
    *(float4*)&sqm[0] = *(const float4*)&sqb[m0 + tx * 8];
    *(float4*)&sqm[4] = *(const float4*)&sqb[m0 + tx * 8 + 4];
    float* dbase = dist + (size_t)bz * NR * NPTS;
    #pragma unroll
    for (int ia = 0; ia < 8; ++ia) {
        int rn = nt * 128 + ty * 8 + ia;
        float ov[8];
        #pragma unroll
        for (int ib = 0; ib < 8; ++ib) ov[ib] = 2.f * acc[ia][ib] - sqm[ib];
        *(float4*)&dbase[(size_t)rn * NPTS + m0 + tx * 8]     = *(float4*)&ov[0];
        *(float4*)&dbase[(size_t)rn * NPTS + m0 + tx * 8 + 4] = *(float4*)&ov[4];
    }
    if (sym && mt < nt) {
        float sqn[8];
        *(float4*)&sqn[0] = *(const float4*)&sqb[nbase + ty * 8];
        *(float4*)&sqn[4] = *(const float4*)&sqb[nbase + ty * 8 + 4];
        #pragma unroll
        for (int ib = 0; ib < 8; ++ib) {
            int rm = m0 + tx * 8 + ib;
            float ov[8];
            #pragma unroll
            for (int ia = 0; ia < 8; ++ia) ov[ia] = 2.f * acc[ia][ib] - sqn[ia];
            *(float4*)&dbase[(size_t)rm * NPTS + nbase + ty * 8]     = *(float4*)&ov[0];
            *(float4*)&dbase[(size_t)rm * NPTS + nbase + ty * 8 + 4] = *(float4*)&ov[4];
        }
    }
}

// col of candidate j (float4-load layout): 4*lane + (j&3) + 256*(j>>2)
#define SCOLX(lane, j) (((lane) << 2) + ((j) & 3) + (((j) >> 2) << 8))

// monotone f32 -> u32 key (no NaNs), then (key<<32)|~col: u64 desc order
// == (value desc, col asc) exactly; keys unique since cols unique.
__device__ __forceinline__ unsigned long long packkey(float v, int c) {
    unsigned u = __float_as_uint(v);
    u ^= ((unsigned)((int)u >> 31)) | 0x80000000u;
    return ((unsigned long long)u << 32) | (unsigned)(~c);
}

// Tree-ILP threshold scan, fully in u64 key space.
__device__ __forceinline__ void scan4k(const float (&v)[32], int lane,
        unsigned long long thrK,
        unsigned long long& a1, unsigned long long& a2,
        unsigned long long& a3, unsigned long long& a4, int& d) {
    unsigned long long tK = thrK;
    d = 0;
    #pragma unroll
    for (int p = 0; p < 4; ++p) {
        unsigned long long b0 = 0, b1 = 0, b2 = 0, b3 = 0;
        #pragma unroll
        for (int jj = 0; jj < 8; ++jj) {
            {
                int j = jj;
                unsigned long long kj = packkey(v[j], SCOLX(lane, j));
                if (kj < tK && kj > b0) b0 = kj;
            }
            {
                int j = 8 + jj;
                unsigned long long kj = packkey(v[j], SCOLX(lane, j));
                if (kj < tK && kj > b1) b1 = kj;
            }
            {
                int j = 16 + jj;
                unsigned long long kj = packkey(v[j], SCOLX(lane, j));
                if (kj < tK && kj > b2) b2 = kj;
            }
            {
                int j = 24 + jj;
                unsigned long long kj = packkey(v[j], SCOLX(lane, j));
                if (kj < tK && kj > b3) b3 = kj;
            }
        }
        if (b1 > b0) b0 = b1;
        if (b3 > b2) b2 = b3;
        if (b2 > b0) b0 = b2;
        if (p == 0)      a1 = b0;
        else if (p == 1) a2 = b0;
        else if (p == 2) a3 = b0;
        else             a4 = b0;
        if (b0 != 0) ++d;
        tK = b0;
    }
}

// Top-20 per row: per-lane sorted top-4 head window (u64 keys) + one
// u64 max-butterfly per selection. Exact (value desc, col asc).
__global__ __launch_bounds__(256) void k_select(const float* __restrict__ dist,
        int* __restrict__ idx, int bOff, int n0, int NR) {
    int lane = threadIdx.x & 63;
    int r = blockIdx.x * 4 + (threadIdx.x >> 6);
    int bl = r / NR;
    int n = n0 + (r - bl * NR);
    const float4* row4 = (const float4*)(dist + (size_t)r * NPTS);
    float v[32];
    #pragma unroll
    for (int jj = 0; jj < 8; ++jj)
        *(float4*)&v[jj * 4] = row4[lane + 64 * jj];
    int* orow = idx + ((size_t)(bOff + bl) * NPTS + n) * KNN;

    unsigned long long a1, a2, a3, a4;
    int d;
    unsigned long long mlK = 0xFFFFFFFFFFFFFFFFull;
    scan4k(v, lane, mlK, a1, a2, a3, a4, d);

    for (int s = 0; s < KNN; ++s) {
        unsigned long long wk = a1;
        #pragma unroll
        for (int off = 32; off; off >>= 1) {
            unsigned long long ok = __shfl_xor(wk, off);
            if (ok > wk) wk = ok;
        }
        int wc = ~(int)(unsigned)(wk & 0xFFFFFFFFull);
        if (lane == 0) orow[s] = wc;
        bool won = (a1 != 0) && (wk == a1);
        if (won) {
            mlK = a1;
            a1 = a2; a2 = a3; a3 = a4; a4 = 0;
            --d;
        }
        if (s < KNN - 1 && __any(won && d == 0)) {
            if (won && d == 0)
                scan4k(v, lane, mlK, a1, a2, a3, a4, d);
        }
    }
}

__global__ __launch_bounds__(256) void k_pz(const float* __restrict__ out, int Cin,
        const float* __restrict__ Ut, const float* __restrict__ Vt,
        float* __restrict__ P, float* __restrict__ Z) {
    int b = blockIdx.y;
    int n0 = blockIdx.x * 64;
    const float* X = out + ((size_t)b * OUTC + (OUTC - Cin)) * NPTS;
    __shared__ float Xs[16][64];
    __shared__ float Us[16][64];
    __shared__ float Vs[16][64];
    int t = threadIdx.x;
    int tx = t & 15, ty = t >> 4;
    float accP[4][4] = {}, accZ[4][4] = {};
    int col = t & 63, r0 = t >> 6;
    for (int kk = 0; kk < Cin; kk += 16) {
        #pragma unroll
        for (int i = 0; i < 4; ++i) {
            int rr = r0 + i * 4;
            Xs[rr][col] = X[(size_t)(kk + rr) * NPTS + n0 + col];
            Us[rr][col] = Ut[(kk + rr) * 64 + col];
            Vs[rr][col] = Vt[(kk + rr) * 64 + col];
        }
        __syncthreads();
        #pragma unroll
        for (int k = 0; k < 16; ++k) {
            float xv[4], uv[4], vv[4];
            *(float4*)xv = *(float4*)&Xs[k][ty * 4];
            *(float4*)uv = *(float4*)&Us[k][tx * 4];
            *(float4*)vv = *(float4*)&Vs[k][tx * 4];
            #pragma unroll
            for (int a = 0; a < 4; ++a)
                #pragma unroll
                for (int o = 0; o < 4; ++o) {
                    accP[a][o] = fmaf(uv[o], xv[a], accP[a][o]);
                    accZ[a][o] = fmaf(vv[o], xv[a], accZ[a][o]);
                }
        }
        __syncthreads();
    }
    #pragma unroll
    for (int a = 0; a < 4; ++a) {
        size_t base = ((size_t)b * NPTS + n0 + ty * 4 + a) * 64 + tx * 4;
        *(float4*)&P[base] = *(float4*)&accP[a][0];
        *(float4*)&Z[base] = *(float4*)&accZ[a][0];
    }
}

__global__ __launch_bounds__(64) void k_gather(const int* __restrict__ idx,
        const float* __restrict__ P, const float* __restrict__ Z,
        const float* __restrict__ bias,
        float* __restrict__ ymax, float* __restrict__ ymin,
        float* __restrict__ partials) {
    int blk = blockIdx.x;
    int b = blk / (NPTS / NPB);
    int n0 = (blk % (NPTS / NPB)) * NPB;
    int o = threadIdx.x;
    float bv = bias[o];
    float S1 = 0.f, S2 = 0.f;
    const float* Zb = Z + (size_t)b * NPTS * 64;
    for (int i = 0; i < NPB; ++i) {
        int n = n0 + i;
        const int* ir = idx + ((size_t)b * NPTS + n) * KNN;
        float mx = -3.0e38f, mn = 3.0e38f, s1 = 0.f, s2 = 0.f;
        #pragma unroll
        for (int k = 0; k < KNN; ++k) {
            int m = ir[k];
            float zv = Zb[(size_t)m * 64 + o];
            mx = fmaxf(mx, zv);
            mn = fminf(mn, zv);
            s1 += zv;
            s2 = fmaf(zv, zv, s2);
        }
        float tv = P[((size_t)b * NPTS + n) * 64 + o] + bv;
        size_t yb = ((size_t)b * NPTS + n) * 64 + o;
        ymax[yb] = tv + mx;
        ymin[yb] = tv + mn;
        S1 += (float)KNN * tv + s1;
        S2 += fmaf((float)KNN * tv, tv, fmaf(2.f * tv, s1, s2));
    }
    partials[(size_t)blk * 128 + o] = S1;
    partials[(size_t)blk * 128 + 64 + o] = S2;
}

// Level-1 reduce: partials[2048][128] -> red[NRED][128]. Coalesced row reads.
__global__ __launch_bounds__(256) void k_reduce(const float* __restrict__ partials,
                                                float* __restrict__ red) {
    __shared__ float L[256];
    int t = threadIdx.x;
    int j = t & 127, half = t >> 7;
    int rows = (NB * NPTS / NPB) / NRED;
    int base = blockIdx.x * rows + half;
    float s = 0.f;
    #pragma unroll
    for (int i = 0; i < 16; ++i)
        s += partials[(size_t)(base + 2 * i) * 128 + j];
    L[t] = s;
    __syncthreads();
    if (half == 0)
        red[(size_t)blockIdx.x * 128 + j] = L[j] + L[128 + j];
}

__global__ void k_stats(const float* __restrict__ red,
        const float* __restrict__ gamma, const float* __restrict__ beta,
        float* __restrict__ ss) {
    __shared__ float L[128];
    int j = threadIdx.x;
    float s = 0.f;
    #pragma unroll
    for (int p = 0; p < NRED; ++p) s += red[(size_t)p * 128 + j];
    L[j] = s;
    __syncthreads();
    if (j < 64) {
        const float cnt = (float)NB * NPTS * KNN;
        float mu = L[j] / cnt;
        float ms = L[64 + j] / cnt;
        float var = ms - mu * mu;
        float sc = gamma[j] / sqrtf(var + 1e-5f);
        ss[j] = sc;
        ss[64 + j] = beta[j] - mu * sc;
    }
}

__global__ __launch_bounds__(256) void k_final(const float* __restrict__ ymax,
        const float* __restrict__ ymin, const float* __restrict__ ss,
        float* __restrict__ out, int obase) {
    int b = blockIdx.y;
    int n0 = blockIdx.x * 64;
    __shared__ float T[64][65];
    int t = threadIdx.x;
    int o = t & 63, r0 = t >> 6;
    float sc = ss[o], sh = ss[64 + o];
    #pragma unroll
    for (int i = 0; i < 16; ++i) {
        int n = r0 + i * 4;
        size_t src = ((size_t)b * NPTS + n0 + n) * 64 + o;
        float v = (sc >= 0.f) ? ymax[src] : ymin[src];
        v = fmaf(sc, v, sh);
        T[o][n] = v > 0.f ? v : 0.f;
    }
    __syncthreads();
    #pragma unroll
    for (int i = 0; i < 16; ++i) {
        int oo = r0 + i * 4;
        out[((size_t)b * OUTC + obase + oo) * NPTS + n0 + o] = T[oo][o];
    }
}

extern "C" void kernel_launch(void* const* d_in, const int* in_sizes, int n_in,
                              void* d_out, int out_size, void* d_ws, size_t ws_size,
                              hipStream_t stream) {
    const float* inp   = (const float*)d_in[0];
    const float* W[3]  = {(const float*)d_in[1], (const float*)d_in[5], (const float*)d_in[9]};
    const float* bi[3] = {(const float*)d_in[2], (const float*)d_in[6], (const float*)d_in[10]};
    const float* ga[3] = {(const float*)d_in[3], (const float*)d_in[7], (const float*)d_in[11]};
    const float* be[3] = {(const float*)d_in[4], (const float*)d_in[8], (const float*)d_in[12]};
    float* out = (float*)d_out;
    (void)in_sizes; (void)n_in; (void)out_size;

    char* w = (char*)d_ws;
    size_t off = 0;
    auto alloc = [&](size_t bytes) -> void* {
        void* p = w + off;
        off = (off + bytes + 255) & ~(size_t)255;
        return p;
    };
    int*   idx      = (int*)  alloc((size_t)NB * NPTS * KNN * 4);
    float* Ut       = (float*)alloc(192 * 64 * 4);
    float* Vt       = (float*)alloc(192 * 64 * 4);
    float* sq       = (float*)alloc((size_t)NB * NPTS * 4);
    float* P        = (float*)alloc((size_t)NB * NPTS * 64 * 4);
    float* Z        = (float*)alloc((size_t)NB * NPTS * 64 * 4);
    float* ymax     = (float*)alloc((size_t)NB * NPTS * 64 * 4);
    float* ymin     = (float*)alloc((size_t)NB * NPTS * 64 * 4);
    float* partials = (float*)alloc((size_t)(NB * NPTS / NPB) * 128 * 4);
    float* red      = (float*)alloc((size_t)NRED * 128 * 4);
    float* ss       = (float*)alloc(128 * 4);

    float* dist = (float*)(w + off);
    size_t distAvail = (ws_size > off) ? (ws_size - off) : 0;
    const size_t matBytes = (size_t)NPTS * NPTS * 4;

    k_copy_in<<<NB * 64 * NPTS / 256, 256, 0, stream>>>(inp, out);

    int Cins[3]  = {64, 128, 192};
    int obase[3] = {128, 64, 0};
    int nblkGather = NB * NPTS / NPB;

    for (int l = 0; l < 3; ++l) {
        int Cin = Cins[l];
        k_prep_uv<<<(Cin * 64 + 255) / 256, 256, 0, stream>>>(W[l], Cin, Ut, Vt);
        k_sqsum<<<NB * NPTS / 256, 256, 0, stream>>>(out, Cin, sq);

        if (distAvail >= (size_t)NB * matBytes) {
            k_dist64<<<dim3(528, 1, NB), 256, 0, stream>>>(out, Cin, sq, dist);
            k_select<<<NB * NPTS / 4, 256, 0, stream>>>(dist, idx, 0, 0, NPTS);
        } else if (distAvail >= matBytes) {
            for (int b = 0; b < NB; ++b) {
                k_dist<<<dim3(136, 1, 1), 256, 0, stream>>>(out, Cin, sq, dist, b, 0, NPTS, 1);
                k_select<<<NPTS / 4, 256, 0, stream>>>(dist, idx, b, 0, NPTS);
            }
        } else {
            int NR = (int)((distAvail / ((size_t)NPTS * 4)) & ~(size_t)127);
            if (NR < 128) NR = 128;
            for (int b = 0; b < NB; ++b) {
                for (int n0 = 0; n0 < NPTS; n0 += NR) {
                    int nr = (NPTS - n0 < NR) ? (NPTS - n0) : NR;
                    k_dist<<<dim3(16, nr / 128, 1), 256, 0, stream>>>(out, Cin, sq, dist, b, n0, nr, 0);
                    k_select<<<nr / 4, 256, 0, stream>>>(dist, idx, b, n0, nr);
                }
            }
        }

        k_pz<<<dim3(NPTS / 64, NB), 256, 0, stream>>>(out, Cin, Ut, Vt, P, Z);
        k_gather<<<nblkGather, 64, 0, stream>>>(idx, P, Z, bi[l], ymax, ymin, partials);
        k_reduce<<<NRED, 256, 0, stream>>>(partials, red);
        k_stats<<<1, 128, 0, stream>>>(red, ga[l], be[l], ss);
        k_final<<<dim3(NPTS / 64, NB), 256, 0, stream>>>(ymax, ymin, ss, out, obase[l]);
    }
}